// Round 8
// baseline (193.408 us; speedup 1.0000x reference)
//
#include <hip/hip_runtime.h>
#include <hip/hip_fp16.h>
#include <math.h>

#define NNODES 20000
#define NEDGE  640000
#define ETOT   (NEDGE + NNODES)   // 660000
#define FDIM   128
#define CDIM   40
#define NEG    0.2f
#define HHALF  (NNODES * 64)      // elements per half-matrix

#define NB     157                // buckets of 128 dsts: (20000+127)>>7
#define BCAP   6144               // per-bucket capacity (mean 4224; +29 sigma margin)
#define EPB    2048               // edges per bucketA block
#define NBLKA  ((ETOT + EPB - 1) / EPB)   // 323

__device__ __forceinline__ float lrelu(float v) { return v >= 0.f ? v : NEG * v; }

__device__ __forceinline__ void edge_sd(const int* __restrict__ ei, int e, int& s, int& d) {
    if (e < NEDGE) { s = ei[e]; d = ei[NEDGE + e]; }
    else { int n = e - NEDGE; s = n; d = n; }
}

// ---- CSR build, bucketed --------------------------------------------------
__global__ __launch_bounds__(256) void zero_bcnt_k(int* bcnt) {
    if (threadIdx.x < NB) bcnt[threadIdx.x] = 0;
}

// phase A: bin edges into NB buckets; per-block LDS pre-aggregation so global
// atomics are range-reservations (~NB per block) and bbuf writes are dense runs.
__global__ __launch_bounds__(256) void bucketA_k(const int* __restrict__ ei,
                                                 int* __restrict__ bcnt,
                                                 unsigned* __restrict__ bbuf) {
    __shared__ int lhist[NB];
    __shared__ int lbase[NB];
    __shared__ int lcur[NB];
    __shared__ unsigned stash[EPB];
    const int t = threadIdx.x;
    const int e0 = blockIdx.x * EPB;
    for (int i = t; i < NB; i += 256) { lhist[i] = 0; lcur[i] = 0; }
    __syncthreads();
    #pragma unroll
    for (int j = 0; j < EPB / 256; ++j) {
        int e = e0 + j * 256 + t;
        unsigned pk = 0xFFFFFFFFu;
        if (e < ETOT) {
            int s, d; edge_sd(ei, e, s, d);
            atomicAdd(&lhist[d >> 7], 1);
            pk = ((unsigned)(d >> 7) << 22) | ((unsigned)(d & 127) << 15) | (unsigned)s;
        }
        stash[j * 256 + t] = pk;
    }
    __syncthreads();
    for (int i = t; i < NB; i += 256) {
        int c = lhist[i];
        lbase[i] = c ? atomicAdd(&bcnt[i], c) : 0;
    }
    __syncthreads();
    #pragma unroll
    for (int j = 0; j < EPB / 256; ++j) {
        unsigned pk = stash[j * 256 + t];
        if (pk != 0xFFFFFFFFu) {
            int b = pk >> 22;
            int r = atomicAdd(&lcur[b], 1);
            bbuf[(size_t)b * BCAP + lbase[b] + r] = pk & 0x3FFFFFu;  // dlocal<<15 | src
        }
    }
}

// phase B: one block per bucket; LDS-stage, local hist+scan, dense scatter.
// Emits packed ssd[i] = (dst<<15) | src.
__global__ __launch_bounds__(1024) void bucketB_k(const int* __restrict__ bcnt,
                                                  const unsigned* __restrict__ bbuf,
                                                  int* __restrict__ start,
                                                  unsigned* __restrict__ ssd) {
    __shared__ int pre[NB];
    __shared__ int hist[128], hstart[128], hcur[128];
    __shared__ unsigned st[BCAP];
    const int t = threadIdx.x;
    const int b = blockIdx.x;
    if (t < NB) pre[t] = bcnt[t];
    if (t < 128) hist[t] = 0;
    __syncthreads();
    // inclusive scan of pre[NB]
    for (int off = 1; off < NB; off <<= 1) {
        int v = 0;
        if (t < NB && t >= off) v = pre[t - off];
        __syncthreads();
        if (t < NB) pre[t] += v;
        __syncthreads();
    }
    const int n0 = bcnt[b];
    const int n = n0 < BCAP ? n0 : BCAP;
    const int base = (b == 0) ? 0 : pre[b - 1];
    for (int i = t; i < n; i += 1024) {
        unsigned pk = bbuf[(size_t)b * BCAP + i];
        st[i] = pk;
        atomicAdd(&hist[(pk >> 15) & 127], 1);
    }
    __syncthreads();
    if (t < 128) hstart[t] = hist[t];
    __syncthreads();
    for (int off = 1; off < 128; off <<= 1) {
        int v = 0;
        if (t < 128 && t >= off) v = hstart[t - off];
        __syncthreads();
        if (t < 128) hstart[t] += v;
        __syncthreads();
    }
    if (t < 128) { int ex = hstart[t] - hist[t]; hstart[t] = ex; hcur[t] = ex; }
    __syncthreads();
    const int d0 = b << 7;
    const int ndst = min(128, NNODES - d0);
    if (t < ndst) start[d0 + t] = base + hstart[t];
    if (b == 0 && t == 0) start[NNODES] = ETOT;
    const unsigned dofs = (unsigned)d0 << 15;
    for (int i = t; i < n; i += 1024) {
        unsigned pk = st[i];
        int r = atomicAdd(&hcur[(pk >> 15) & 127], 1);
        ssd[base + r] = pk + dofs;                    // (d0+dlocal)<<15 | src
    }
}

// ---- edge-parallel attention weights: p[i] = exp(lrelu(asrc[s]+adst[d])) --
__global__ __launch_bounds__(256) void edge_p_k(const unsigned* __restrict__ ssd,
                                                const float* __restrict__ asrc,
                                                const float* __restrict__ adst,
                                                float* __restrict__ p) {
    int i = blockIdx.x * 256 + threadIdx.x;
    if (i >= ETOT) return;
    const unsigned v = ssd[i];
    const int s = (int)(v & 0x7FFFu);
    const int d = (int)(v >> 15);
    p[i] = __expf(lrelu(asrc[s] + adst[d]));
}

// ---- fused GEMM + attention logits; writes column-split fp16 halves -------
// Hbase[0..HHALF)   = cols 0-63   as [N][64]
// Hbase[HHALF..)    = cols 64-127 as [N][64]
__global__ __launch_bounds__(256) void gemm_alphas_k(const float* __restrict__ X,
                                                     const float* __restrict__ W,
                                                     const float* __restrict__ a_src,
                                                     const float* __restrict__ a_dst,
                                                     __half* __restrict__ Hbase,
                                                     float* __restrict__ asrc,
                                                     float* __restrict__ adst) {
    __shared__ float Ws[FDIM * FDIM];                 // 64 KiB, row-major [k][c]
    for (int i = threadIdx.x; i < FDIM * FDIM; i += 256) Ws[i] = W[i];
    __syncthreads();
    const int rsub = threadIdx.x >> 5;                // 0..7
    const int c4 = (threadIdx.x & 31) * 4;
    const int row0 = blockIdx.x * 32 + rsub * 4;      // 625*32 = 20000 exactly
    const float* xr = X + (size_t)row0 * FDIM;
    const float4 as4 = *(const float4*)(a_src + c4);
    const float4 ad4 = *(const float4*)(a_dst + c4);
    float4 acc[4];
    #pragma unroll
    for (int r = 0; r < 4; ++r) acc[r] = make_float4(0.f, 0.f, 0.f, 0.f);
    #pragma unroll 4
    for (int k = 0; k < FDIM; k += 4) {
        const float4 w0 = *(const float4*)(Ws + (k + 0) * FDIM + c4);
        const float4 w1 = *(const float4*)(Ws + (k + 1) * FDIM + c4);
        const float4 w2 = *(const float4*)(Ws + (k + 2) * FDIM + c4);
        const float4 w3 = *(const float4*)(Ws + (k + 3) * FDIM + c4);
        #pragma unroll
        for (int r = 0; r < 4; ++r) {
            const float4 xv = *(const float4*)(xr + (size_t)r * FDIM + k);
            acc[r].x = fmaf(xv.x, w0.x, acc[r].x); acc[r].y = fmaf(xv.x, w0.y, acc[r].y);
            acc[r].z = fmaf(xv.x, w0.z, acc[r].z); acc[r].w = fmaf(xv.x, w0.w, acc[r].w);
            acc[r].x = fmaf(xv.y, w1.x, acc[r].x); acc[r].y = fmaf(xv.y, w1.y, acc[r].y);
            acc[r].z = fmaf(xv.y, w1.z, acc[r].z); acc[r].w = fmaf(xv.y, w1.w, acc[r].w);
            acc[r].x = fmaf(xv.z, w2.x, acc[r].x); acc[r].y = fmaf(xv.z, w2.y, acc[r].y);
            acc[r].z = fmaf(xv.z, w2.z, acc[r].z); acc[r].w = fmaf(xv.z, w2.w, acc[r].w);
            acc[r].x = fmaf(xv.w, w3.x, acc[r].x); acc[r].y = fmaf(xv.w, w3.y, acc[r].y);
            acc[r].z = fmaf(xv.w, w3.z, acc[r].z); acc[r].w = fmaf(xv.w, w3.w, acc[r].w);
        }
    }
    __half* hdst = Hbase + (c4 < 64 ? (size_t)0 : (size_t)HHALF) ;
    const int ch = c4 & 63;
    #pragma unroll
    for (int r = 0; r < 4; ++r) {
        union { __half2 h[2]; float2 f; } u;
        u.h[0] = __floats2half2_rn(acc[r].x, acc[r].y);
        u.h[1] = __floats2half2_rn(acc[r].z, acc[r].w);
        *(float2*)(hdst + (size_t)(row0 + r) * 64 + ch) = u.f;
        float ps = acc[r].x * as4.x + acc[r].y * as4.y + acc[r].z * as4.z + acc[r].w * as4.w;
        float pd = acc[r].x * ad4.x + acc[r].y * ad4.y + acc[r].z * ad4.z + acc[r].w * ad4.w;
        #pragma unroll
        for (int off = 16; off; off >>= 1) {
            ps += __shfl_down(ps, off, 32);
            pd += __shfl_down(pd, off, 32);
        }
        if ((threadIdx.x & 31) == 0) { asrc[row0 + r] = ps; adst[row0 + r] = pd; }
    }
}

// ---- half-width weighted gather-sum over an L2-resident 2.56MB half-matrix
// Wave per dst; lane owns ONE column (ushort gather = 128B/row = 2 lines).
__global__ __launch_bounds__(256) void gat_agg_half_k(const __half* __restrict__ Hh,
                                                      const float* __restrict__ p,
                                                      const unsigned* __restrict__ ssd,
                                                      const int* __restrict__ start,
                                                      const float* __restrict__ bias,
                                                      float* __restrict__ out,
                                                      int colbase) {
    int w = (blockIdx.x * 256 + threadIdx.x) >> 6;   // destination node
    if (w >= NNODES) return;
    const int lane = threadIdx.x & 63;
    const unsigned short* Hu = (const unsigned short*)Hh;
    const int lo = start[w], hi = start[w + 1];
    float den = 0.f, a = 0.f;
    int i = lo;
    for (; i + 16 <= hi; i += 16) {
        int s[16]; float pp[16];
        #pragma unroll
        for (int j = 0; j < 16; ++j) {
            s[j] = (int)(__builtin_nontemporal_load(&ssd[i + j]) & 0x7FFFu);
            pp[j] = __builtin_nontemporal_load(&p[i + j]);
        }
        unsigned short hv[16];
        #pragma unroll
        for (int j = 0; j < 16; ++j)
            hv[j] = Hu[(size_t)s[j] * 64 + lane];
        #pragma unroll
        for (int j = 0; j < 16; ++j) {
            union { unsigned short u; __half h; } c; c.u = hv[j];
            den += pp[j];
            a = fmaf(pp[j], __half2float(c.h), a);
        }
    }
    for (; i + 4 <= hi; i += 4) {
        int s[4]; float pp[4];
        #pragma unroll
        for (int j = 0; j < 4; ++j) {
            s[j] = (int)(__builtin_nontemporal_load(&ssd[i + j]) & 0x7FFFu);
            pp[j] = __builtin_nontemporal_load(&p[i + j]);
        }
        unsigned short hv[4];
        #pragma unroll
        for (int j = 0; j < 4; ++j)
            hv[j] = Hu[(size_t)s[j] * 64 + lane];
        #pragma unroll
        for (int j = 0; j < 4; ++j) {
            union { unsigned short u; __half h; } c; c.u = hv[j];
            den += pp[j];
            a = fmaf(pp[j], __half2float(c.h), a);
        }
    }
    for (; i < hi; ++i) {
        const int s = (int)(__builtin_nontemporal_load(&ssd[i]) & 0x7FFFu);
        const float pj = __builtin_nontemporal_load(&p[i]);
        union { unsigned short u; __half h; } c; c.u = Hu[(size_t)s * 64 + lane];
        den += pj;
        a = fmaf(pj, __half2float(c.h), a);
    }
    const float inv = 1.f / den;                      // den>0: self-loop present
    float v = fmaf(a, inv, bias[colbase + lane]);
    v = v > 0.f ? v : 0.f;
    __builtin_nontemporal_store(v, out + (size_t)w * FDIM + colbase + lane);
}

// ---- classifier: out[N,40] = H[N,128] @ Wl[128,40] + bl -------------------
// 320 threads: thread = (rsub 0..31, cq 0..9); 2 rows x 4 cols per thread.
__global__ __launch_bounds__(320) void classifier_k(const float* __restrict__ H,
                                                    const float* __restrict__ Wl,
                                                    const float* __restrict__ bl,
                                                    float* __restrict__ out) {
    __shared__ float Ws[FDIM * CDIM];                 // 20 KiB
    __shared__ float bs[CDIM];
    for (int i = threadIdx.x; i < FDIM * CDIM; i += 320) Ws[i] = Wl[i];
    if (threadIdx.x < CDIM) bs[threadIdx.x] = bl[threadIdx.x];
    __syncthreads();
    const int cq = threadIdx.x % 10;
    const int rsub = threadIdx.x / 10;                // 0..31
    const int c4 = cq * 4;
    const int row0 = blockIdx.x * 64 + rsub * 2;
    const int r0 = min(row0, NNODES - 1);
    const int r1 = min(row0 + 1, NNODES - 1);
    const float* x0 = H + (size_t)r0 * FDIM;
    const float* x1 = H + (size_t)r1 * FDIM;
    float4 a0 = make_float4(0.f, 0.f, 0.f, 0.f);
    float4 a1 = make_float4(0.f, 0.f, 0.f, 0.f);
    #pragma unroll 4
    for (int k = 0; k < FDIM; k += 4) {
        const float4 w0 = *(const float4*)(Ws + (k + 0) * CDIM + c4);
        const float4 w1 = *(const float4*)(Ws + (k + 1) * CDIM + c4);
        const float4 w2 = *(const float4*)(Ws + (k + 2) * CDIM + c4);
        const float4 w3 = *(const float4*)(Ws + (k + 3) * CDIM + c4);
        const float4 v0 = *(const float4*)(x0 + k);
        const float4 v1 = *(const float4*)(x1 + k);
        a0.x = fmaf(v0.x, w0.x, a0.x); a0.y = fmaf(v0.x, w0.y, a0.y);
        a0.z = fmaf(v0.x, w0.z, a0.z); a0.w = fmaf(v0.x, w0.w, a0.w);
        a0.x = fmaf(v0.y, w1.x, a0.x); a0.y = fmaf(v0.y, w1.y, a0.y);
        a0.z = fmaf(v0.y, w1.z, a0.z); a0.w = fmaf(v0.y, w1.w, a0.w);
        a0.x = fmaf(v0.z, w2.x, a0.x); a0.y = fmaf(v0.z, w2.y, a0.y);
        a0.z = fmaf(v0.z, w2.z, a0.z); a0.w = fmaf(v0.z, w2.w, a0.w);
        a0.x = fmaf(v0.w, w3.x, a0.x); a0.y = fmaf(v0.w, w3.y, a0.y);
        a0.z = fmaf(v0.w, w3.z, a0.z); a0.w = fmaf(v0.w, w3.w, a0.w);
        a1.x = fmaf(v1.x, w0.x, a1.x); a1.y = fmaf(v1.x, w0.y, a1.y);
        a1.z = fmaf(v1.x, w0.z, a1.z); a1.w = fmaf(v1.x, w0.w, a1.w);
        a1.x = fmaf(v1.y, w1.x, a1.x); a1.y = fmaf(v1.y, w1.y, a1.y);
        a1.z = fmaf(v1.y, w1.z, a1.z); a1.w = fmaf(v1.y, w1.w, a1.w);
        a1.x = fmaf(v1.z, w2.x, a1.x); a1.y = fmaf(v1.z, w2.y, a1.y);
        a1.z = fmaf(v1.z, w2.z, a1.z); a1.w = fmaf(v1.z, w2.w, a1.w);
        a1.x = fmaf(v1.w, w3.x, a1.x); a1.y = fmaf(v1.w, w3.y, a1.y);
        a1.z = fmaf(v1.w, w3.z, a1.z); a1.w = fmaf(v1.w, w3.w, a1.w);
    }
    const float4 bb = *(const float4*)(bs + c4);
    a0.x += bb.x; a0.y += bb.y; a0.z += bb.z; a0.w += bb.w;
    a1.x += bb.x; a1.y += bb.y; a1.z += bb.z; a1.w += bb.w;
    if (row0 < NNODES)     *(float4*)(out + (size_t)row0 * CDIM + c4) = a0;
    if (row0 + 1 < NNODES) *(float4*)(out + (size_t)(row0 + 1) * CDIM + c4) = a1;
}

extern "C" void kernel_launch(void* const* d_in, const int* in_sizes, int n_in,
                              void* d_out, int out_size, void* d_ws, size_t ws_size,
                              hipStream_t stream) {
    const float* x   = (const float*)d_in[0];
    const int*   ei  = (const int*)d_in[1];
    const float* W1  = (const float*)d_in[2];
    const float* a1s = (const float*)d_in[3];
    const float* a1d = (const float*)d_in[4];
    const float* b1  = (const float*)d_in[5];
    const float* W2  = (const float*)d_in[6];
    const float* a2s = (const float*)d_in[7];
    const float* a2d = (const float*)d_in[8];
    const float* b2  = (const float*)d_in[9];
    const float* Wl  = (const float*)d_in[10];
    const float* bl  = (const float*)d_in[11];
    float* out = (float*)d_out;

    char* ws = (char*)d_ws;
    __half*   H16   = (__half*)(ws);                 // Hlo[N][64] | Hhi[N][64], 5.12 MB
    float*    bufB  = (float*)(ws + 5120000);        // 10.24 MB
    float*    asrc  = (float*)(ws + 15360000);       // 80 KB
    float*    adst  = (float*)(ws + 15440000);       // 80 KB
    int*      start = (int*)  (ws + 15520000);       // [N+1]
    unsigned* ssd   = (unsigned*)(ws + 15600004);    // [ETOT] packed dst<<15|src
    int*      bcnt  = (int*)  (ws + 18240004);       // [NB]
    unsigned* bbuf  = (unsigned*)(ws + 18240632);    // NB*BCAP u32 = 3.86 MB
    float*    pbuf  = (float*)bbuf;                  // [ETOT] overlays bbuf (dead after CSR)

    __half* Hlo = H16;
    __half* Hhi = H16 + HHALF;

    const int gEdge = (ETOT + 255) / 256;            // 2579

    // ---- CSR build (bucketed, shared by both layers) ----
    zero_bcnt_k<<<1, 256, 0, stream>>>(bcnt);
    bucketA_k<<<NBLKA, 256, 0, stream>>>(ei, bcnt, bbuf);
    bucketB_k<<<NB, 1024, 0, stream>>>(bcnt, bbuf, start, ssd);

    // ---- layer 1 ----
    gemm_alphas_k<<<625, 256, 0, stream>>>(x, W1, a1s, a1d, H16, asrc, adst);
    edge_p_k<<<gEdge, 256, 0, stream>>>(ssd, asrc, adst, pbuf);
    gat_agg_half_k<<<5000, 256, 0, stream>>>(Hlo, pbuf, ssd, start, b1, bufB, 0);
    gat_agg_half_k<<<5000, 256, 0, stream>>>(Hhi, pbuf, ssd, start, b1, bufB, 64);

    // ---- layer 2 ----
    gemm_alphas_k<<<625, 256, 0, stream>>>(bufB, W2, a2s, a2d, H16, asrc, adst);
    edge_p_k<<<gEdge, 256, 0, stream>>>(ssd, asrc, adst, pbuf);
    gat_agg_half_k<<<5000, 256, 0, stream>>>(Hlo, pbuf, ssd, start, b2, bufB, 0);
    gat_agg_half_k<<<5000, 256, 0, stream>>>(Hhi, pbuf, ssd, start, b2, bufB, 64);

    // ---- classifier ----
    classifier_k<<<313, 320, 0, stream>>>(bufB, Wl, bl, out);
}

// Round 9
// 155.435 us; speedup vs baseline: 1.2443x; 1.2443x over previous
//
#include <hip/hip_runtime.h>
#include <hip/hip_fp16.h>
#include <math.h>

#define NNODES 20000
#define NEDGE  640000
#define ETOT   (NEDGE + NNODES)   // 660000
#define FDIM   128
#define CDIM   40
#define NEG    0.2f

#define NB     157                // buckets of 128 dsts: (20000+127)>>7
#define BCAP   6144               // per-bucket capacity (mean 4224; +29 sigma margin)
#define EPB    2048               // edges per bucketA block
#define NBLKA  ((ETOT + EPB - 1) / EPB)   // 323

__device__ __forceinline__ float lrelu(float v) { return v >= 0.f ? v : NEG * v; }

__device__ __forceinline__ void edge_sd(const int* __restrict__ ei, int e, int& s, int& d) {
    if (e < NEDGE) { s = ei[e]; d = ei[NEDGE + e]; }
    else { int n = e - NEDGE; s = n; d = n; }
}

// ---- CSR build, bucketed --------------------------------------------------
__global__ __launch_bounds__(256) void zero_bcnt_k(int* bcnt) {
    if (threadIdx.x < NB) bcnt[threadIdx.x] = 0;
}

__global__ __launch_bounds__(256) void bucketA_k(const int* __restrict__ ei,
                                                 int* __restrict__ bcnt,
                                                 unsigned* __restrict__ bbuf) {
    __shared__ int lhist[NB];
    __shared__ int lbase[NB];
    __shared__ int lcur[NB];
    __shared__ unsigned stash[EPB];
    const int t = threadIdx.x;
    const int e0 = blockIdx.x * EPB;
    for (int i = t; i < NB; i += 256) { lhist[i] = 0; lcur[i] = 0; }
    __syncthreads();
    #pragma unroll
    for (int j = 0; j < EPB / 256; ++j) {
        int e = e0 + j * 256 + t;
        unsigned pk = 0xFFFFFFFFu;
        if (e < ETOT) {
            int s, d; edge_sd(ei, e, s, d);
            atomicAdd(&lhist[d >> 7], 1);
            pk = ((unsigned)(d >> 7) << 22) | ((unsigned)(d & 127) << 15) | (unsigned)s;
        }
        stash[j * 256 + t] = pk;
    }
    __syncthreads();
    for (int i = t; i < NB; i += 256) {
        int c = lhist[i];
        lbase[i] = c ? atomicAdd(&bcnt[i], c) : 0;
    }
    __syncthreads();
    #pragma unroll
    for (int j = 0; j < EPB / 256; ++j) {
        unsigned pk = stash[j * 256 + t];
        if (pk != 0xFFFFFFFFu) {
            int b = pk >> 22;
            int r = atomicAdd(&lcur[b], 1);
            bbuf[(size_t)b * BCAP + lbase[b] + r] = pk & 0x3FFFFFu;  // dlocal<<15 | src
        }
    }
}

// phase B: one block per bucket; emits packed ssd[i] = (dst<<15) | src.
__global__ __launch_bounds__(1024) void bucketB_k(const int* __restrict__ bcnt,
                                                  const unsigned* __restrict__ bbuf,
                                                  int* __restrict__ start,
                                                  unsigned* __restrict__ ssd) {
    __shared__ int pre[NB];
    __shared__ int hist[128], hstart[128], hcur[128];
    __shared__ unsigned st[BCAP];
    const int t = threadIdx.x;
    const int b = blockIdx.x;
    if (t < NB) pre[t] = bcnt[t];
    if (t < 128) hist[t] = 0;
    __syncthreads();
    for (int off = 1; off < NB; off <<= 1) {
        int v = 0;
        if (t < NB && t >= off) v = pre[t - off];
        __syncthreads();
        if (t < NB) pre[t] += v;
        __syncthreads();
    }
    const int n0 = bcnt[b];
    const int n = n0 < BCAP ? n0 : BCAP;
    const int base = (b == 0) ? 0 : pre[b - 1];
    for (int i = t; i < n; i += 1024) {
        unsigned pk = bbuf[(size_t)b * BCAP + i];
        st[i] = pk;
        atomicAdd(&hist[(pk >> 15) & 127], 1);
    }
    __syncthreads();
    if (t < 128) hstart[t] = hist[t];
    __syncthreads();
    for (int off = 1; off < 128; off <<= 1) {
        int v = 0;
        if (t < 128 && t >= off) v = hstart[t - off];
        __syncthreads();
        if (t < 128) hstart[t] += v;
        __syncthreads();
    }
    if (t < 128) { int ex = hstart[t] - hist[t]; hstart[t] = ex; hcur[t] = ex; }
    __syncthreads();
    const int d0 = b << 7;
    const int ndst = min(128, NNODES - d0);
    if (t < ndst) start[d0 + t] = base + hstart[t];
    if (b == 0 && t == 0) start[NNODES] = ETOT;
    const unsigned dofs = (unsigned)d0 << 15;
    for (int i = t; i < n; i += 1024) {
        unsigned pk = st[i];
        int r = atomicAdd(&hcur[(pk >> 15) & 127], 1);
        ssd[base + r] = pk + dofs;                    // (d0+dlocal)<<15 | src
    }
}

// ---- edge-parallel attention weights: p[i] = exp(lrelu(asrc[s]+adst[d])) --
__global__ __launch_bounds__(256) void edge_p_k(const unsigned* __restrict__ ssd,
                                                const float* __restrict__ asrc,
                                                const float* __restrict__ adst,
                                                float* __restrict__ p) {
    int i = blockIdx.x * 256 + threadIdx.x;
    if (i >= ETOT) return;
    const unsigned v = ssd[i];
    const int s = (int)(v & 0x7FFFu);
    const int d = (int)(v >> 15);
    p[i] = __expf(lrelu(asrc[s] + adst[d]));
}

// ---- fused GEMM + attention logits, f32 input (layer 1) -------------------
__global__ __launch_bounds__(256) void gemm_alphas_f32_k(const float* __restrict__ X,
                                                         const float* __restrict__ W,
                                                         const float* __restrict__ a_src,
                                                         const float* __restrict__ a_dst,
                                                         __half* __restrict__ H16,
                                                         float* __restrict__ asrc,
                                                         float* __restrict__ adst) {
    __shared__ float Ws[FDIM * FDIM];                 // 64 KiB, row-major [k][c]
    for (int i = threadIdx.x; i < FDIM * FDIM; i += 256) Ws[i] = W[i];
    __syncthreads();
    const int rsub = threadIdx.x >> 5;                // 0..7
    const int c4 = (threadIdx.x & 31) * 4;
    const int row0 = blockIdx.x * 32 + rsub * 4;      // 625*32 = 20000 exactly
    const float* xr = X + (size_t)row0 * FDIM;
    const float4 as4 = *(const float4*)(a_src + c4);
    const float4 ad4 = *(const float4*)(a_dst + c4);
    float4 acc[4];
    #pragma unroll
    for (int r = 0; r < 4; ++r) acc[r] = make_float4(0.f, 0.f, 0.f, 0.f);
    #pragma unroll 4
    for (int k = 0; k < FDIM; k += 4) {
        const float4 w0 = *(const float4*)(Ws + (k + 0) * FDIM + c4);
        const float4 w1 = *(const float4*)(Ws + (k + 1) * FDIM + c4);
        const float4 w2 = *(const float4*)(Ws + (k + 2) * FDIM + c4);
        const float4 w3 = *(const float4*)(Ws + (k + 3) * FDIM + c4);
        #pragma unroll
        for (int r = 0; r < 4; ++r) {
            const float4 xv = *(const float4*)(xr + (size_t)r * FDIM + k);
            acc[r].x = fmaf(xv.x, w0.x, acc[r].x); acc[r].y = fmaf(xv.x, w0.y, acc[r].y);
            acc[r].z = fmaf(xv.x, w0.z, acc[r].z); acc[r].w = fmaf(xv.x, w0.w, acc[r].w);
            acc[r].x = fmaf(xv.y, w1.x, acc[r].x); acc[r].y = fmaf(xv.y, w1.y, acc[r].y);
            acc[r].z = fmaf(xv.y, w1.z, acc[r].z); acc[r].w = fmaf(xv.y, w1.w, acc[r].w);
            acc[r].x = fmaf(xv.z, w2.x, acc[r].x); acc[r].y = fmaf(xv.z, w2.y, acc[r].y);
            acc[r].z = fmaf(xv.z, w2.z, acc[r].z); acc[r].w = fmaf(xv.z, w2.w, acc[r].w);
            acc[r].x = fmaf(xv.w, w3.x, acc[r].x); acc[r].y = fmaf(xv.w, w3.y, acc[r].y);
            acc[r].z = fmaf(xv.w, w3.z, acc[r].z); acc[r].w = fmaf(xv.w, w3.w, acc[r].w);
        }
    }
    #pragma unroll
    for (int r = 0; r < 4; ++r) {
        union { __half2 h[2]; float2 f; } u;
        u.h[0] = __floats2half2_rn(acc[r].x, acc[r].y);
        u.h[1] = __floats2half2_rn(acc[r].z, acc[r].w);
        *(float2*)(H16 + (size_t)(row0 + r) * FDIM + c4) = u.f;
        float ps = acc[r].x * as4.x + acc[r].y * as4.y + acc[r].z * as4.z + acc[r].w * as4.w;
        float pd = acc[r].x * ad4.x + acc[r].y * ad4.y + acc[r].z * ad4.z + acc[r].w * ad4.w;
        #pragma unroll
        for (int off = 16; off; off >>= 1) {
            ps += __shfl_down(ps, off, 32);
            pd += __shfl_down(pd, off, 32);
        }
        if ((threadIdx.x & 31) == 0) { asrc[row0 + r] = ps; adst[row0 + r] = pd; }
    }
}

// ---- fused GEMM + attention logits, fp16 input (layer 2) ------------------
__global__ __launch_bounds__(256) void gemm_alphas_f16_k(const __half* __restrict__ X,
                                                         const float* __restrict__ W,
                                                         const float* __restrict__ a_src,
                                                         const float* __restrict__ a_dst,
                                                         __half* __restrict__ H16,
                                                         float* __restrict__ asrc,
                                                         float* __restrict__ adst) {
    __shared__ float Ws[FDIM * FDIM];
    for (int i = threadIdx.x; i < FDIM * FDIM; i += 256) Ws[i] = W[i];
    __syncthreads();
    const int rsub = threadIdx.x >> 5;
    const int c4 = (threadIdx.x & 31) * 4;
    const int row0 = blockIdx.x * 32 + rsub * 4;
    const __half* xr = X + (size_t)row0 * FDIM;
    const float4 as4 = *(const float4*)(a_src + c4);
    const float4 ad4 = *(const float4*)(a_dst + c4);
    float4 acc[4];
    #pragma unroll
    for (int r = 0; r < 4; ++r) acc[r] = make_float4(0.f, 0.f, 0.f, 0.f);
    #pragma unroll 4
    for (int k = 0; k < FDIM; k += 4) {
        const float4 w0 = *(const float4*)(Ws + (k + 0) * FDIM + c4);
        const float4 w1 = *(const float4*)(Ws + (k + 1) * FDIM + c4);
        const float4 w2 = *(const float4*)(Ws + (k + 2) * FDIM + c4);
        const float4 w3 = *(const float4*)(Ws + (k + 3) * FDIM + c4);
        #pragma unroll
        for (int r = 0; r < 4; ++r) {
            union { float2 f2; __half2 h2[2]; } ux;
            ux.f2 = *(const float2*)(xr + (size_t)r * FDIM + k);
            const float2 xlo = __half22float2(ux.h2[0]);
            const float2 xhi = __half22float2(ux.h2[1]);
            acc[r].x = fmaf(xlo.x, w0.x, acc[r].x); acc[r].y = fmaf(xlo.x, w0.y, acc[r].y);
            acc[r].z = fmaf(xlo.x, w0.z, acc[r].z); acc[r].w = fmaf(xlo.x, w0.w, acc[r].w);
            acc[r].x = fmaf(xlo.y, w1.x, acc[r].x); acc[r].y = fmaf(xlo.y, w1.y, acc[r].y);
            acc[r].z = fmaf(xlo.y, w1.z, acc[r].z); acc[r].w = fmaf(xlo.y, w1.w, acc[r].w);
            acc[r].x = fmaf(xhi.x, w2.x, acc[r].x); acc[r].y = fmaf(xhi.x, w2.y, acc[r].y);
            acc[r].z = fmaf(xhi.x, w2.z, acc[r].z); acc[r].w = fmaf(xhi.x, w2.w, acc[r].w);
            acc[r].x = fmaf(xhi.y, w3.x, acc[r].x); acc[r].y = fmaf(xhi.y, w3.y, acc[r].y);
            acc[r].z = fmaf(xhi.y, w3.z, acc[r].z); acc[r].w = fmaf(xhi.y, w3.w, acc[r].w);
        }
    }
    #pragma unroll
    for (int r = 0; r < 4; ++r) {
        union { __half2 h[2]; float2 f; } u;
        u.h[0] = __floats2half2_rn(acc[r].x, acc[r].y);
        u.h[1] = __floats2half2_rn(acc[r].z, acc[r].w);
        *(float2*)(H16 + (size_t)(row0 + r) * FDIM + c4) = u.f;
        float ps = acc[r].x * as4.x + acc[r].y * as4.y + acc[r].z * as4.z + acc[r].w * as4.w;
        float pd = acc[r].x * ad4.x + acc[r].y * ad4.y + acc[r].z * ad4.z + acc[r].w * ad4.w;
        #pragma unroll
        for (int off = 16; off; off >>= 1) {
            ps += __shfl_down(ps, off, 32);
            pd += __shfl_down(pd, off, 32);
        }
        if ((threadIdx.x & 31) == 0) { asrc[row0 + r] = ps; adst[row0 + r] = pd; }
    }
}

// ---- weighted gather-sum, 2 waves per dst, LDS combine, fp16 output -------
// Block = 4 waves = 2 dsts; wave pair splits the dst's edge range in half.
__global__ __launch_bounds__(256) void gat_agg_k(const __half* __restrict__ H16,
                                                 const float* __restrict__ p,
                                                 const unsigned* __restrict__ ssd,
                                                 const int* __restrict__ start,
                                                 const float* __restrict__ bias,
                                                 __half* __restrict__ out16) {
    __shared__ float sden[4];
    __shared__ float sacc[4][128];
    const int wv = threadIdx.x >> 6;                 // 0..3
    const int lane = threadIdx.x & 63;
    const int w = blockIdx.x * 2 + (wv >> 1);        // destination node
    const int part = wv & 1;
    float den = 0.f, a0 = 0.f, a1 = 0.f;
    const size_t coff = (size_t)lane * 2;
    if (w < NNODES) {
        const int lo0 = start[w], hi0 = start[w + 1];
        const int mid = (lo0 + hi0 + 1) >> 1;
        int i = part ? mid : lo0;
        const int hi = part ? hi0 : mid;
        for (; i + 8 <= hi; i += 8) {
            int s[8]; float pp[8];
            #pragma unroll
            for (int j = 0; j < 8; ++j) {
                s[j] = (int)(ssd[i + j] & 0x7FFFu);
                pp[j] = p[i + j];
            }
            __half2 hv[8];
            #pragma unroll
            for (int j = 0; j < 8; ++j)
                hv[j] = *(const __half2*)(H16 + (size_t)s[j] * FDIM + coff);
            #pragma unroll
            for (int j = 0; j < 8; ++j) {
                const float2 f = __half22float2(hv[j]);
                den += pp[j];
                a0 = fmaf(pp[j], f.x, a0);
                a1 = fmaf(pp[j], f.y, a1);
            }
        }
        for (; i < hi; ++i) {
            const int s = (int)(ssd[i] & 0x7FFFu);
            const float pj = p[i];
            const float2 f = __half22float2(*(const __half2*)(H16 + (size_t)s * FDIM + coff));
            den += pj;
            a0 = fmaf(pj, f.x, a0);
            a1 = fmaf(pj, f.y, a1);
        }
    }
    sacc[wv][lane * 2] = a0;
    sacc[wv][lane * 2 + 1] = a1;
    if (lane == 0) sden[wv] = den;
    __syncthreads();
    if (part == 0 && w < NNODES) {
        const float inv = 1.f / (sden[wv] + sden[wv + 1]);   // den>0: self-loop
        float v0 = fmaf(sacc[wv][lane * 2] + sacc[wv + 1][lane * 2], inv, bias[lane * 2]);
        float v1 = fmaf(sacc[wv][lane * 2 + 1] + sacc[wv + 1][lane * 2 + 1], inv, bias[lane * 2 + 1]);
        v0 = v0 > 0.f ? v0 : 0.f;
        v1 = v1 > 0.f ? v1 : 0.f;
        *(__half2*)(out16 + (size_t)w * FDIM + coff) = __floats2half2_rn(v0, v1);
    }
}

// ---- classifier: out[N,40] = H16[N,128] @ Wl[128,40] + bl (fp16 input) ----
__global__ __launch_bounds__(320) void classifier_k(const __half* __restrict__ H,
                                                    const float* __restrict__ Wl,
                                                    const float* __restrict__ bl,
                                                    float* __restrict__ out) {
    __shared__ float Ws[FDIM * CDIM];                 // 20 KiB
    __shared__ float bs[CDIM];
    for (int i = threadIdx.x; i < FDIM * CDIM; i += 320) Ws[i] = Wl[i];
    if (threadIdx.x < CDIM) bs[threadIdx.x] = bl[threadIdx.x];
    __syncthreads();
    const int cq = threadIdx.x % 10;
    const int rsub = threadIdx.x / 10;                // 0..31
    const int c4 = cq * 4;
    const int row0 = blockIdx.x * 64 + rsub * 2;
    const int r0 = min(row0, NNODES - 1);
    const int r1 = min(row0 + 1, NNODES - 1);
    const __half* x0 = H + (size_t)r0 * FDIM;
    const __half* x1 = H + (size_t)r1 * FDIM;
    float4 a0 = make_float4(0.f, 0.f, 0.f, 0.f);
    float4 a1 = make_float4(0.f, 0.f, 0.f, 0.f);
    #pragma unroll 4
    for (int k = 0; k < FDIM; k += 4) {
        const float4 w0 = *(const float4*)(Ws + (k + 0) * CDIM + c4);
        const float4 w1 = *(const float4*)(Ws + (k + 1) * CDIM + c4);
        const float4 w2 = *(const float4*)(Ws + (k + 2) * CDIM + c4);
        const float4 w3 = *(const float4*)(Ws + (k + 3) * CDIM + c4);
        union { float2 f2; __half2 h2[2]; } u0, u1;
        u0.f2 = *(const float2*)(x0 + k);
        u1.f2 = *(const float2*)(x1 + k);
        const float2 v0lo = __half22float2(u0.h2[0]);
        const float2 v0hi = __half22float2(u0.h2[1]);
        const float2 v1lo = __half22float2(u1.h2[0]);
        const float2 v1hi = __half22float2(u1.h2[1]);
        a0.x = fmaf(v0lo.x, w0.x, a0.x); a0.y = fmaf(v0lo.x, w0.y, a0.y);
        a0.z = fmaf(v0lo.x, w0.z, a0.z); a0.w = fmaf(v0lo.x, w0.w, a0.w);
        a0.x = fmaf(v0lo.y, w1.x, a0.x); a0.y = fmaf(v0lo.y, w1.y, a0.y);
        a0.z = fmaf(v0lo.y, w1.z, a0.z); a0.w = fmaf(v0lo.y, w1.w, a0.w);
        a0.x = fmaf(v0hi.x, w2.x, a0.x); a0.y = fmaf(v0hi.x, w2.y, a0.y);
        a0.z = fmaf(v0hi.x, w2.z, a0.z); a0.w = fmaf(v0hi.x, w2.w, a0.w);
        a0.x = fmaf(v0hi.y, w3.x, a0.x); a0.y = fmaf(v0hi.y, w3.y, a0.y);
        a0.z = fmaf(v0hi.y, w3.z, a0.z); a0.w = fmaf(v0hi.y, w3.w, a0.w);
        a1.x = fmaf(v1lo.x, w0.x, a1.x); a1.y = fmaf(v1lo.x, w0.y, a1.y);
        a1.z = fmaf(v1lo.x, w0.z, a1.z); a1.w = fmaf(v1lo.x, w0.w, a1.w);
        a1.x = fmaf(v1lo.y, w1.x, a1.x); a1.y = fmaf(v1lo.y, w1.y, a1.y);
        a1.z = fmaf(v1lo.y, w1.z, a1.z); a1.w = fmaf(v1lo.y, w1.w, a1.w);
        a1.x = fmaf(v1hi.x, w2.x, a1.x); a1.y = fmaf(v1hi.x, w2.y, a1.y);
        a1.z = fmaf(v1hi.x, w2.z, a1.z); a1.w = fmaf(v1hi.x, w2.w, a1.w);
        a1.x = fmaf(v1hi.y, w3.x, a1.x); a1.y = fmaf(v1hi.y, w3.y, a1.y);
        a1.z = fmaf(v1hi.y, w3.z, a1.z); a1.w = fmaf(v1hi.y, w3.w, a1.w);
    }
    const float4 bb = *(const float4*)(bs + c4);
    a0.x += bb.x; a0.y += bb.y; a0.z += bb.z; a0.w += bb.w;
    a1.x += bb.x; a1.y += bb.y; a1.z += bb.z; a1.w += bb.w;
    if (row0 < NNODES)     *(float4*)(out + (size_t)row0 * CDIM + c4) = a0;
    if (row0 + 1 < NNODES) *(float4*)(out + (size_t)(row0 + 1) * CDIM + c4) = a1;
}

extern "C" void kernel_launch(void* const* d_in, const int* in_sizes, int n_in,
                              void* d_out, int out_size, void* d_ws, size_t ws_size,
                              hipStream_t stream) {
    const float* x   = (const float*)d_in[0];
    const int*   ei  = (const int*)d_in[1];
    const float* W1  = (const float*)d_in[2];
    const float* a1s = (const float*)d_in[3];
    const float* a1d = (const float*)d_in[4];
    const float* b1  = (const float*)d_in[5];
    const float* W2  = (const float*)d_in[6];
    const float* a2s = (const float*)d_in[7];
    const float* a2d = (const float*)d_in[8];
    const float* b2  = (const float*)d_in[9];
    const float* Wl  = (const float*)d_in[10];
    const float* bl  = (const float*)d_in[11];
    float* out = (float*)d_out;

    char* ws = (char*)d_ws;
    __half*   bufH  = (__half*)(ws);                 // [N,128] fp16 gather copy, 5.12 MB
    __half*   bufO  = (__half*)(ws + 5120000);       // [N,128] fp16 layer output, 5.12 MB
    float*    asrc  = (float*)(ws + 15360000);       // 80 KB
    float*    adst  = (float*)(ws + 15440000);       // 80 KB
    int*      start = (int*)  (ws + 15520000);       // [N+1]
    unsigned* ssd   = (unsigned*)(ws + 15600004);    // [ETOT] packed dst<<15|src
    int*      bcnt  = (int*)  (ws + 18240004);       // [NB]
    unsigned* bbuf  = (unsigned*)(ws + 18240632);    // NB*BCAP u32 = 3.86 MB
    float*    pbuf  = (float*)bbuf;                  // [ETOT] overlays bbuf (dead after CSR)

    const int gEdge = (ETOT + 255) / 256;            // 2579
    const int gAgg  = (NNODES + 1) / 2;              // 10000 blocks, 2 dsts each

    // ---- CSR build (bucketed, shared by both layers) ----
    zero_bcnt_k<<<1, 256, 0, stream>>>(bcnt);
    bucketA_k<<<NBLKA, 256, 0, stream>>>(ei, bcnt, bbuf);
    bucketB_k<<<NB, 1024, 0, stream>>>(bcnt, bbuf, start, ssd);

    // ---- layer 1 ----
    gemm_alphas_f32_k<<<625, 256, 0, stream>>>(x, W1, a1s, a1d, bufH, asrc, adst);
    edge_p_k<<<gEdge, 256, 0, stream>>>(ssd, asrc, adst, pbuf);
    gat_agg_k<<<gAgg, 256, 0, stream>>>(bufH, pbuf, ssd, start, b1, bufO);

    // ---- layer 2 ----
    gemm_alphas_f16_k<<<625, 256, 0, stream>>>(bufO, W2, a2s, a2d, bufH, asrc, adst);
    edge_p_k<<<gEdge, 256, 0, stream>>>(ssd, asrc, adst, pbuf);
    gat_agg_k<<<gAgg, 256, 0, stream>>>(bufH, pbuf, ssd, start, b2, bufO);

    // ---- classifier ----
    classifier_k<<<313, 320, 0, stream>>>(bufO, Wl, bl, out);
}

// Round 10
// 137.607 us; speedup vs baseline: 1.4055x; 1.1296x over previous
//
#include <hip/hip_runtime.h>
#include <hip/hip_fp16.h>
#include <math.h>

#define NNODES 20000
#define NEDGE  640000
#define ETOT   (NEDGE + NNODES)   // 660000
#define FDIM   128
#define CDIM   40
#define NEG    0.2f

#define NB     157                // buckets of 128 dsts: (20000+127)>>7
#define BCAP   6144               // per-bucket capacity (mean 4224; +29 sigma margin)
#define EPB    2048               // edges per bucketA block
#define NBLKA  ((ETOT + EPB - 1) / EPB)   // 323

__device__ __forceinline__ float lrelu(float v) { return v >= 0.f ? v : NEG * v; }

__device__ __forceinline__ void edge_sd(const int* __restrict__ ei, int e, int& s, int& d) {
    if (e < NEDGE) { s = ei[e]; d = ei[NEDGE + e]; }
    else { int n = e - NEDGE; s = n; d = n; }
}

// ---- CSR build, bucketed --------------------------------------------------
__global__ __launch_bounds__(256) void zero_bcnt_k(int* bcnt) {
    if (threadIdx.x < NB) bcnt[threadIdx.x] = 0;
}

__global__ __launch_bounds__(256) void bucketA_k(const int* __restrict__ ei,
                                                 int* __restrict__ bcnt,
                                                 unsigned* __restrict__ bbuf) {
    __shared__ int lhist[NB];
    __shared__ int lbase[NB];
    __shared__ int lcur[NB];
    __shared__ unsigned stash[EPB];
    const int t = threadIdx.x;
    const int e0 = blockIdx.x * EPB;
    for (int i = t; i < NB; i += 256) { lhist[i] = 0; lcur[i] = 0; }
    __syncthreads();
    #pragma unroll
    for (int j = 0; j < EPB / 256; ++j) {
        int e = e0 + j * 256 + t;
        unsigned pk = 0xFFFFFFFFu;
        if (e < ETOT) {
            int s, d; edge_sd(ei, e, s, d);
            atomicAdd(&lhist[d >> 7], 1);
            pk = ((unsigned)(d >> 7) << 22) | ((unsigned)(d & 127) << 15) | (unsigned)s;
        }
        stash[j * 256 + t] = pk;
    }
    __syncthreads();
    for (int i = t; i < NB; i += 256) {
        int c = lhist[i];
        lbase[i] = c ? atomicAdd(&bcnt[i], c) : 0;
    }
    __syncthreads();
    #pragma unroll
    for (int j = 0; j < EPB / 256; ++j) {
        unsigned pk = stash[j * 256 + t];
        if (pk != 0xFFFFFFFFu) {
            int b = pk >> 22;
            int r = atomicAdd(&lcur[b], 1);
            bbuf[(size_t)b * BCAP + lbase[b] + r] = pk & 0x3FFFFFu;  // dlocal<<15 | src
        }
    }
}

// phase B: one block per bucket; emits packed ssd[i] = (dst<<15) | src.
__global__ __launch_bounds__(1024) void bucketB_k(const int* __restrict__ bcnt,
                                                  const unsigned* __restrict__ bbuf,
                                                  int* __restrict__ start,
                                                  unsigned* __restrict__ ssd) {
    __shared__ int pre[NB];
    __shared__ int hist[128], hstart[128], hcur[128];
    __shared__ unsigned st[BCAP];
    const int t = threadIdx.x;
    const int b = blockIdx.x;
    if (t < NB) pre[t] = bcnt[t];
    if (t < 128) hist[t] = 0;
    __syncthreads();
    for (int off = 1; off < NB; off <<= 1) {
        int v = 0;
        if (t < NB && t >= off) v = pre[t - off];
        __syncthreads();
        if (t < NB) pre[t] += v;
        __syncthreads();
    }
    const int n0 = bcnt[b];
    const int n = n0 < BCAP ? n0 : BCAP;
    const int base = (b == 0) ? 0 : pre[b - 1];
    for (int i = t; i < n; i += 1024) {
        unsigned pk = bbuf[(size_t)b * BCAP + i];
        st[i] = pk;
        atomicAdd(&hist[(pk >> 15) & 127], 1);
    }
    __syncthreads();
    if (t < 128) hstart[t] = hist[t];
    __syncthreads();
    for (int off = 1; off < 128; off <<= 1) {
        int v = 0;
        if (t < 128 && t >= off) v = hstart[t - off];
        __syncthreads();
        if (t < 128) hstart[t] += v;
        __syncthreads();
    }
    if (t < 128) { int ex = hstart[t] - hist[t]; hstart[t] = ex; hcur[t] = ex; }
    __syncthreads();
    const int d0 = b << 7;
    const int ndst = min(128, NNODES - d0);
    if (t < ndst) start[d0 + t] = base + hstart[t];
    if (b == 0 && t == 0) start[NNODES] = ETOT;
    const unsigned dofs = (unsigned)d0 << 15;
    for (int i = t; i < n; i += 1024) {
        unsigned pk = st[i];
        int r = atomicAdd(&hcur[(pk >> 15) & 127], 1);
        ssd[base + r] = pk + dofs;                    // (d0+dlocal)<<15 | src
    }
}

// ---- edge-parallel attention weights: p[i] = exp(lrelu(asrc[s]+adst[d])) --
__global__ __launch_bounds__(256) void edge_p_k(const unsigned* __restrict__ ssd,
                                                const float* __restrict__ asrc,
                                                const float* __restrict__ adst,
                                                float* __restrict__ p) {
    int i = blockIdx.x * 256 + threadIdx.x;
    if (i >= ETOT) return;
    const unsigned v = ssd[i];
    const int s = (int)(v & 0x7FFFu);
    const int d = (int)(v >> 15);
    p[i] = __expf(lrelu(asrc[s] + adst[d]));
}

// ---- fused GEMM + attention logits, f32 input (layer 1) -------------------
__global__ __launch_bounds__(256) void gemm_alphas_f32_k(const float* __restrict__ X,
                                                         const float* __restrict__ W,
                                                         const float* __restrict__ a_src,
                                                         const float* __restrict__ a_dst,
                                                         __half* __restrict__ H16,
                                                         float* __restrict__ asrc,
                                                         float* __restrict__ adst) {
    __shared__ float Ws[FDIM * FDIM];                 // 64 KiB, row-major [k][c]
    for (int i = threadIdx.x; i < FDIM * FDIM; i += 256) Ws[i] = W[i];
    __syncthreads();
    const int rsub = threadIdx.x >> 5;                // 0..7
    const int c4 = (threadIdx.x & 31) * 4;
    const int row0 = blockIdx.x * 32 + rsub * 4;      // 625*32 = 20000 exactly
    const float* xr = X + (size_t)row0 * FDIM;
    const float4 as4 = *(const float4*)(a_src + c4);
    const float4 ad4 = *(const float4*)(a_dst + c4);
    float4 acc[4];
    #pragma unroll
    for (int r = 0; r < 4; ++r) acc[r] = make_float4(0.f, 0.f, 0.f, 0.f);
    #pragma unroll 4
    for (int k = 0; k < FDIM; k += 4) {
        const float4 w0 = *(const float4*)(Ws + (k + 0) * FDIM + c4);
        const float4 w1 = *(const float4*)(Ws + (k + 1) * FDIM + c4);
        const float4 w2 = *(const float4*)(Ws + (k + 2) * FDIM + c4);
        const float4 w3 = *(const float4*)(Ws + (k + 3) * FDIM + c4);
        #pragma unroll
        for (int r = 0; r < 4; ++r) {
            const float4 xv = *(const float4*)(xr + (size_t)r * FDIM + k);
            acc[r].x = fmaf(xv.x, w0.x, acc[r].x); acc[r].y = fmaf(xv.x, w0.y, acc[r].y);
            acc[r].z = fmaf(xv.x, w0.z, acc[r].z); acc[r].w = fmaf(xv.x, w0.w, acc[r].w);
            acc[r].x = fmaf(xv.y, w1.x, acc[r].x); acc[r].y = fmaf(xv.y, w1.y, acc[r].y);
            acc[r].z = fmaf(xv.y, w1.z, acc[r].z); acc[r].w = fmaf(xv.y, w1.w, acc[r].w);
            acc[r].x = fmaf(xv.z, w2.x, acc[r].x); acc[r].y = fmaf(xv.z, w2.y, acc[r].y);
            acc[r].z = fmaf(xv.z, w2.z, acc[r].z); acc[r].w = fmaf(xv.z, w2.w, acc[r].w);
            acc[r].x = fmaf(xv.w, w3.x, acc[r].x); acc[r].y = fmaf(xv.w, w3.y, acc[r].y);
            acc[r].z = fmaf(xv.w, w3.z, acc[r].z); acc[r].w = fmaf(xv.w, w3.w, acc[r].w);
        }
    }
    #pragma unroll
    for (int r = 0; r < 4; ++r) {
        union { __half2 h[2]; float2 f; } u;
        u.h[0] = __floats2half2_rn(acc[r].x, acc[r].y);
        u.h[1] = __floats2half2_rn(acc[r].z, acc[r].w);
        *(float2*)(H16 + (size_t)(row0 + r) * FDIM + c4) = u.f;
        float ps = acc[r].x * as4.x + acc[r].y * as4.y + acc[r].z * as4.z + acc[r].w * as4.w;
        float pd = acc[r].x * ad4.x + acc[r].y * ad4.y + acc[r].z * ad4.z + acc[r].w * ad4.w;
        #pragma unroll
        for (int off = 16; off; off >>= 1) {
            ps += __shfl_down(ps, off, 32);
            pd += __shfl_down(pd, off, 32);
        }
        if ((threadIdx.x & 31) == 0) { asrc[row0 + r] = ps; adst[row0 + r] = pd; }
    }
}

// ---- fused GEMM + attention logits, fp16 input (layer 2) ------------------
__global__ __launch_bounds__(256) void gemm_alphas_f16_k(const __half* __restrict__ X,
                                                         const float* __restrict__ W,
                                                         const float* __restrict__ a_src,
                                                         const float* __restrict__ a_dst,
                                                         __half* __restrict__ H16,
                                                         float* __restrict__ asrc,
                                                         float* __restrict__ adst) {
    __shared__ float Ws[FDIM * FDIM];
    for (int i = threadIdx.x; i < FDIM * FDIM; i += 256) Ws[i] = W[i];
    __syncthreads();
    const int rsub = threadIdx.x >> 5;
    const int c4 = (threadIdx.x & 31) * 4;
    const int row0 = blockIdx.x * 32 + rsub * 4;
    const __half* xr = X + (size_t)row0 * FDIM;
    const float4 as4 = *(const float4*)(a_src + c4);
    const float4 ad4 = *(const float4*)(a_dst + c4);
    float4 acc[4];
    #pragma unroll
    for (int r = 0; r < 4; ++r) acc[r] = make_float4(0.f, 0.f, 0.f, 0.f);
    #pragma unroll 4
    for (int k = 0; k < FDIM; k += 4) {
        const float4 w0 = *(const float4*)(Ws + (k + 0) * FDIM + c4);
        const float4 w1 = *(const float4*)(Ws + (k + 1) * FDIM + c4);
        const float4 w2 = *(const float4*)(Ws + (k + 2) * FDIM + c4);
        const float4 w3 = *(const float4*)(Ws + (k + 3) * FDIM + c4);
        #pragma unroll
        for (int r = 0; r < 4; ++r) {
            union { float2 f2; __half2 h2[2]; } ux;
            ux.f2 = *(const float2*)(xr + (size_t)r * FDIM + k);
            const float2 xlo = __half22float2(ux.h2[0]);
            const float2 xhi = __half22float2(ux.h2[1]);
            acc[r].x = fmaf(xlo.x, w0.x, acc[r].x); acc[r].y = fmaf(xlo.x, w0.y, acc[r].y);
            acc[r].z = fmaf(xlo.x, w0.z, acc[r].z); acc[r].w = fmaf(xlo.x, w0.w, acc[r].w);
            acc[r].x = fmaf(xlo.y, w1.x, acc[r].x); acc[r].y = fmaf(xlo.y, w1.y, acc[r].y);
            acc[r].z = fmaf(xlo.y, w1.z, acc[r].z); acc[r].w = fmaf(xlo.y, w1.w, acc[r].w);
            acc[r].x = fmaf(xhi.x, w2.x, acc[r].x); acc[r].y = fmaf(xhi.x, w2.y, acc[r].y);
            acc[r].z = fmaf(xhi.x, w2.z, acc[r].z); acc[r].w = fmaf(xhi.x, w2.w, acc[r].w);
            acc[r].x = fmaf(xhi.y, w3.x, acc[r].x); acc[r].y = fmaf(xhi.y, w3.y, acc[r].y);
            acc[r].z = fmaf(xhi.y, w3.z, acc[r].z); acc[r].w = fmaf(xhi.y, w3.w, acc[r].w);
        }
    }
    #pragma unroll
    for (int r = 0; r < 4; ++r) {
        union { __half2 h[2]; float2 f; } u;
        u.h[0] = __floats2half2_rn(acc[r].x, acc[r].y);
        u.h[1] = __floats2half2_rn(acc[r].z, acc[r].w);
        *(float2*)(H16 + (size_t)(row0 + r) * FDIM + c4) = u.f;
        float ps = acc[r].x * as4.x + acc[r].y * as4.y + acc[r].z * as4.z + acc[r].w * as4.w;
        float pd = acc[r].x * ad4.x + acc[r].y * ad4.y + acc[r].z * ad4.z + acc[r].w * ad4.w;
        #pragma unroll
        for (int off = 16; off; off >>= 1) {
            ps += __shfl_down(ps, off, 32);
            pd += __shfl_down(pd, off, 32);
        }
        if ((threadIdx.x & 31) == 0) { asrc[row0 + r] = ps; adst[row0 + r] = pd; }
    }
}

// ---- pure weighted gather-sum (round-7 structure), fp16 output ------------
// Wave per dst; per 16 edges only the row gathers depend on the ssd loads.
__global__ __launch_bounds__(256) void gat_agg_k(const __half* __restrict__ H16,
                                                 const float* __restrict__ p,
                                                 const unsigned* __restrict__ ssd,
                                                 const int* __restrict__ start,
                                                 const float* __restrict__ bias,
                                                 __half* __restrict__ out16) {
    int w = (blockIdx.x * 256 + threadIdx.x) >> 6;   // destination node
    if (w >= NNODES) return;
    const int lane = threadIdx.x & 63;
    const int lo = start[w], hi = start[w + 1];
    const size_t coff = (size_t)lane * 2;
    float den = 0.f, a0 = 0.f, a1 = 0.f;
    int i = lo;
    for (; i + 16 <= hi; i += 16) {
        int s[16]; float pp[16];
        #pragma unroll
        for (int j = 0; j < 16; ++j) {
            s[j] = (int)(ssd[i + j] & 0x7FFFu);
            pp[j] = p[i + j];
        }
        __half2 hv[16];
        #pragma unroll
        for (int j = 0; j < 16; ++j)
            hv[j] = *(const __half2*)(H16 + (size_t)s[j] * FDIM + coff);
        #pragma unroll
        for (int j = 0; j < 16; ++j) {
            const float2 f = __half22float2(hv[j]);
            den += pp[j];
            a0 = fmaf(pp[j], f.x, a0);
            a1 = fmaf(pp[j], f.y, a1);
        }
    }
    for (; i + 4 <= hi; i += 4) {
        int s[4]; float pp[4];
        #pragma unroll
        for (int j = 0; j < 4; ++j) {
            s[j] = (int)(ssd[i + j] & 0x7FFFu);
            pp[j] = p[i + j];
        }
        __half2 hv[4];
        #pragma unroll
        for (int j = 0; j < 4; ++j)
            hv[j] = *(const __half2*)(H16 + (size_t)s[j] * FDIM + coff);
        #pragma unroll
        for (int j = 0; j < 4; ++j) {
            const float2 f = __half22float2(hv[j]);
            den += pp[j];
            a0 = fmaf(pp[j], f.x, a0);
            a1 = fmaf(pp[j], f.y, a1);
        }
    }
    for (; i < hi; ++i) {
        const int s = (int)(ssd[i] & 0x7FFFu);
        const float pj = p[i];
        const float2 f = __half22float2(*(const __half2*)(H16 + (size_t)s * FDIM + coff));
        den += pj;
        a0 = fmaf(pj, f.x, a0);
        a1 = fmaf(pj, f.y, a1);
    }
    const float inv = 1.f / den;                      // den>0: self-loop present
    float v0 = fmaf(a0, inv, bias[lane * 2]);
    float v1 = fmaf(a1, inv, bias[lane * 2 + 1]);
    v0 = v0 > 0.f ? v0 : 0.f;
    v1 = v1 > 0.f ? v1 : 0.f;
    *(__half2*)(out16 + (size_t)w * FDIM + coff) = __floats2half2_rn(v0, v1);
}

// ---- classifier: out[N,40] = H16[N,128] @ Wl[128,40] + bl (fp16 input) ----
__global__ __launch_bounds__(320) void classifier_k(const __half* __restrict__ H,
                                                    const float* __restrict__ Wl,
                                                    const float* __restrict__ bl,
                                                    float* __restrict__ out) {
    __shared__ float Ws[FDIM * CDIM];                 // 20 KiB
    __shared__ float bs[CDIM];
    for (int i = threadIdx.x; i < FDIM * CDIM; i += 320) Ws[i] = Wl[i];
    if (threadIdx.x < CDIM) bs[threadIdx.x] = bl[threadIdx.x];
    __syncthreads();
    const int cq = threadIdx.x % 10;
    const int rsub = threadIdx.x / 10;                // 0..31
    const int c4 = cq * 4;
    const int row0 = blockIdx.x * 64 + rsub * 2;
    const int r0 = min(row0, NNODES - 1);
    const int r1 = min(row0 + 1, NNODES - 1);
    const __half* x0 = H + (size_t)r0 * FDIM;
    const __half* x1 = H + (size_t)r1 * FDIM;
    float4 a0 = make_float4(0.f, 0.f, 0.f, 0.f);
    float4 a1 = make_float4(0.f, 0.f, 0.f, 0.f);
    #pragma unroll 4
    for (int k = 0; k < FDIM; k += 4) {
        const float4 w0 = *(const float4*)(Ws + (k + 0) * CDIM + c4);
        const float4 w1 = *(const float4*)(Ws + (k + 1) * CDIM + c4);
        const float4 w2 = *(const float4*)(Ws + (k + 2) * CDIM + c4);
        const float4 w3 = *(const float4*)(Ws + (k + 3) * CDIM + c4);
        union { float2 f2; __half2 h2[2]; } u0, u1;
        u0.f2 = *(const float2*)(x0 + k);
        u1.f2 = *(const float2*)(x1 + k);
        const float2 v0lo = __half22float2(u0.h2[0]);
        const float2 v0hi = __half22float2(u0.h2[1]);
        const float2 v1lo = __half22float2(u1.h2[0]);
        const float2 v1hi = __half22float2(u1.h2[1]);
        a0.x = fmaf(v0lo.x, w0.x, a0.x); a0.y = fmaf(v0lo.x, w0.y, a0.y);
        a0.z = fmaf(v0lo.x, w0.z, a0.z); a0.w = fmaf(v0lo.x, w0.w, a0.w);
        a0.x = fmaf(v0lo.y, w1.x, a0.x); a0.y = fmaf(v0lo.y, w1.y, a0.y);
        a0.z = fmaf(v0lo.y, w1.z, a0.z); a0.w = fmaf(v0lo.y, w1.w, a0.w);
        a0.x = fmaf(v0hi.x, w2.x, a0.x); a0.y = fmaf(v0hi.x, w2.y, a0.y);
        a0.z = fmaf(v0hi.x, w2.z, a0.z); a0.w = fmaf(v0hi.x, w2.w, a0.w);
        a0.x = fmaf(v0hi.y, w3.x, a0.x); a0.y = fmaf(v0hi.y, w3.y, a0.y);
        a0.z = fmaf(v0hi.y, w3.z, a0.z); a0.w = fmaf(v0hi.y, w3.w, a0.w);
        a1.x = fmaf(v1lo.x, w0.x, a1.x); a1.y = fmaf(v1lo.x, w0.y, a1.y);
        a1.z = fmaf(v1lo.x, w0.z, a1.z); a1.w = fmaf(v1lo.x, w0.w, a1.w);
        a1.x = fmaf(v1lo.y, w1.x, a1.x); a1.y = fmaf(v1lo.y, w1.y, a1.y);
        a1.z = fmaf(v1lo.y, w1.z, a1.z); a1.w = fmaf(v1lo.y, w1.w, a1.w);
        a1.x = fmaf(v1hi.x, w2.x, a1.x); a1.y = fmaf(v1hi.x, w2.y, a1.y);
        a1.z = fmaf(v1hi.x, w2.z, a1.z); a1.w = fmaf(v1hi.x, w2.w, a1.w);
        a1.x = fmaf(v1hi.y, w3.x, a1.x); a1.y = fmaf(v1hi.y, w3.y, a1.y);
        a1.z = fmaf(v1hi.y, w3.z, a1.z); a1.w = fmaf(v1hi.y, w3.w, a1.w);
    }
    const float4 bb = *(const float4*)(bs + c4);
    a0.x += bb.x; a0.y += bb.y; a0.z += bb.z; a0.w += bb.w;
    a1.x += bb.x; a1.y += bb.y; a1.z += bb.z; a1.w += bb.w;
    if (row0 < NNODES)     *(float4*)(out + (size_t)row0 * CDIM + c4) = a0;
    if (row0 + 1 < NNODES) *(float4*)(out + (size_t)(row0 + 1) * CDIM + c4) = a1;
}

extern "C" void kernel_launch(void* const* d_in, const int* in_sizes, int n_in,
                              void* d_out, int out_size, void* d_ws, size_t ws_size,
                              hipStream_t stream) {
    const float* x   = (const float*)d_in[0];
    const int*   ei  = (const int*)d_in[1];
    const float* W1  = (const float*)d_in[2];
    const float* a1s = (const float*)d_in[3];
    const float* a1d = (const float*)d_in[4];
    const float* b1  = (const float*)d_in[5];
    const float* W2  = (const float*)d_in[6];
    const float* a2s = (const float*)d_in[7];
    const float* a2d = (const float*)d_in[8];
    const float* b2  = (const float*)d_in[9];
    const float* Wl  = (const float*)d_in[10];
    const float* bl  = (const float*)d_in[11];
    float* out = (float*)d_out;

    char* ws = (char*)d_ws;
    __half*   bufH  = (__half*)(ws);                 // [N,128] fp16 gather copy, 5.12 MB
    __half*   bufO  = (__half*)(ws + 5120000);       // [N,128] fp16 layer output, 5.12 MB
    float*    asrc  = (float*)(ws + 15360000);       // 80 KB
    float*    adst  = (float*)(ws + 15440000);       // 80 KB
    int*      start = (int*)  (ws + 15520000);       // [N+1]
    unsigned* ssd   = (unsigned*)(ws + 15600004);    // [ETOT] packed dst<<15|src
    int*      bcnt  = (int*)  (ws + 18240004);       // [NB]
    unsigned* bbuf  = (unsigned*)(ws + 18240632);    // NB*BCAP u32 = 3.86 MB
    float*    pbuf  = (float*)bbuf;                  // [ETOT] overlays bbuf (dead after CSR)

    const int gEdge = (ETOT + 255) / 256;            // 2579
    const int gAgg  = (NNODES * 64 + 255) / 256;     // 5000 (wave per dst)

    // ---- CSR build (bucketed, shared by both layers) ----
    zero_bcnt_k<<<1, 256, 0, stream>>>(bcnt);
    bucketA_k<<<NBLKA, 256, 0, stream>>>(ei, bcnt, bbuf);
    bucketB_k<<<NB, 1024, 0, stream>>>(bcnt, bbuf, start, ssd);

    // ---- layer 1 ----
    gemm_alphas_f32_k<<<625, 256, 0, stream>>>(x, W1, a1s, a1d, bufH, asrc, adst);
    edge_p_k<<<gEdge, 256, 0, stream>>>(ssd, asrc, adst, pbuf);
    gat_agg_k<<<gAgg, 256, 0, stream>>>(bufH, pbuf, ssd, start, b1, bufO);

    // ---- layer 2 ----
    gemm_alphas_f16_k<<<625, 256, 0, stream>>>(bufO, W2, a2s, a2d, bufH, asrc, adst);
    edge_p_k<<<gEdge, 256, 0, stream>>>(ssd, asrc, adst, pbuf);
    gat_agg_k<<<gAgg, 256, 0, stream>>>(bufH, pbuf, ssd, start, b2, bufO);

    // ---- classifier ----
    classifier_k<<<313, 320, 0, stream>>>(bufO, Wl, bl, out);
}